// Round 8
// baseline (13905.412 us; speedup 1.0000x reference)
//
#include <hip/hip_runtime.h>
#include <math.h>

#define B 128
#define S 400
#define EENC 512
#define T 300
#define V 30
#define EMB 256
#define H1 512
#define H2 128
#define P 128
#define XD (P + EMB)   // 384
#define K1R (P + H1)   // 640 : LSTM1 serial reduction (ctx + h1); emb precomputed
#define K2 (H1 + H2)   // 640 : LSTM2 reduction
#define N1 (4 * H1)    // 2048
#define N2 (4 * H2)    // 512
#define PRED_SIZE (B * V * T)
#define NBLK 128
#define NTHR 512

typedef __attribute__((ext_vector_type(8))) short short8v;
typedef __attribute__((ext_vector_type(4))) short short4v;
typedef __attribute__((ext_vector_type(4))) float f32x4;

#define MFMA16(a, b, c) __builtin_amdgcn_mfma_f32_16x16x32_bf16((a), (b), (c), 0, 0, 0)

__device__ __forceinline__ float sigmoidf_(float x) { return 1.0f / (1.0f + expf(-x)); }

__device__ __forceinline__ unsigned short f2bf(float x) {
  unsigned int u = __float_as_uint(x);
  u = (u + 0x7FFFu + ((u >> 16) & 1u)) >> 16;
  return (unsigned short)u;
}
__device__ __forceinline__ float bf2f(unsigned short s) {
  return __uint_as_float(((unsigned int)s) << 16);
}

// ---- device-coherent 8B access (bypasses L2 to coherence point; no fences needed) ----
__device__ __forceinline__ unsigned long long aload64(const void* p) {
  return __hip_atomic_load((const unsigned long long*)p, __ATOMIC_RELAXED,
                           __HIP_MEMORY_SCOPE_AGENT);
}
__device__ __forceinline__ void astore64(void* p, unsigned long long v) {
  __hip_atomic_store((unsigned long long*)p, v, __ATOMIC_RELAXED,
                     __HIP_MEMORY_SCOPE_AGENT);
}
union u64s4 { unsigned long long u; short4v s; };
__device__ __forceinline__ short8v load_coh16(const void* p) {
  u64s4 a, b;
  a.u = aload64(p);
  b.u = aload64((const char*)p + 8);
  return __builtin_shufflevector(a.s, b.s, 0, 1, 2, 3, 4, 5, 6, 7);
}
__device__ __forceinline__ unsigned long long pack4us(const unsigned short* s) {
  return (unsigned long long)s[0] | ((unsigned long long)s[1] << 16) |
         ((unsigned long long)s[2] << 32) | ((unsigned long long)s[3] << 48);
}

// ---------------- one-time weight prep ----------------
__global__ void prep_weights(
    const float* __restrict__ Wih1, const float* __restrict__ Whh1,
    const float* __restrict__ bih1, const float* __restrict__ bhh1,
    const float* __restrict__ Wih2, const float* __restrict__ Whh2,
    const float* __restrict__ bih2, const float* __restrict__ bhh2,
    unsigned short* __restrict__ W1h, unsigned short* __restrict__ W1l,
    unsigned short* __restrict__ W2h, unsigned short* __restrict__ W2l,
    float* __restrict__ b1r, float* __restrict__ b2r) {
  const int T1 = N1 * K1R;
  const int T2 = N2 * K2;
  const int TOT = T1 + T2 + N1 + N2;
  for (int idx = blockIdx.x * blockDim.x + threadIdx.x; idx < TOT;
       idx += gridDim.x * blockDim.x) {
    if (idx < T1) {
      int np = idx / K1R, k = idx - np * K1R;
      int h = np >> 2, s = np & 3;
      int no = s * H1 + h;
      float v = (k < P) ? Wih1[no * XD + k] : Whh1[no * H1 + (k - P)];
      unsigned short hb = f2bf(v);
      W1h[idx] = hb;
      W1l[idx] = f2bf(v - bf2f(hb));
    } else if (idx < T1 + T2) {
      int i2 = idx - T1;
      int np = i2 / K2, k = i2 - np * K2;
      int h = np >> 2, s = np & 3;
      int no = s * H2 + h;
      float v = (k < H1) ? Wih2[no * H1 + k] : Whh2[no * H2 + (k - H1)];
      unsigned short hb = f2bf(v);
      W2h[i2] = hb;
      W2l[i2] = f2bf(v - bf2f(hb));
    } else if (idx < T1 + T2 + N1) {
      int np = idx - T1 - T2;
      int h = np >> 2, s = np & 3;
      b1r[np] = bih1[s * H1 + h] + bhh1[s * H1 + h];
    } else {
      int np = idx - T1 - T2 - N1;
      int h = np >> 2, s = np & 3;
      b2r[np] = bih2[s * H2 + h] + bhh2[s * H2 + h];
    }
  }
}

// ---------------- EmbW1[v][n'] = emb[v] . Wih1_embcols[n'] ----------------
__global__ __launch_bounds__(256) void emb_w1(
    const float* __restrict__ emb, const float* __restrict__ Wih1,
    float* __restrict__ EmbW1) {
  int idx = blockIdx.x * 256 + threadIdx.x;
  if (idx >= V * N1) return;
  int v = idx >> 11;
  int np = idx & (N1 - 1);
  int h = np >> 2, s = np & 3;
  int no = s * H1 + h;
  const float* er = emb + v * EMB;
  const float* wr = Wih1 + no * XD + P;
  float a = 0.0f;
#pragma unroll 8
  for (int k = 0; k < EMB; k += 4) {
    float4 e4 = *(const float4*)&er[k];
    float4 w4 = *(const float4*)&wr[k];
    a += e4.x * w4.x + e4.y * w4.y + e4.z * w4.z + e4.w * w4.w;
  }
  EmbW1[idx] = a;
}

// ---------------- keys/values precompute GEMM ----------------
__global__ __launch_bounds__(256) void kv_gemm(
    const float* __restrict__ enc, const float* __restrict__ Wk,
    const float* __restrict__ bk, const float* __restrict__ Wv,
    const float* __restrict__ bv, unsigned short* __restrict__ keys,
    unsigned short* __restrict__ valuesT) {
  __shared__ float As[32][68];
  __shared__ float Ws[32][68];
  const int tid = threadIdx.x;
  const int m0 = blockIdx.x * 64;
  const int n0 = blockIdx.y * 64;
  const int tm = tid & 15, tn = tid >> 4;
  float acc[4][4] = {};
  for (int kc = 0; kc < EENC; kc += 32) {
    for (int i = tid; i < 64 * 32; i += 256) {
      int mm = i >> 5, kk = i & 31;
      As[kk][mm] = enc[(size_t)(m0 + mm) * EENC + kc + kk];
    }
    for (int i = tid; i < 64 * 32; i += 256) {
      int nn = i >> 5, kk = i & 31;
      int n = n0 + nn;
      Ws[kk][nn] = (n < P) ? Wk[n * EENC + kc + kk] : Wv[(n - P) * EENC + kc + kk];
    }
    __syncthreads();
#pragma unroll
    for (int kk = 0; kk < 32; ++kk) {
      float4 av = *(const float4*)&As[kk][tm * 4];
      float4 wv = *(const float4*)&Ws[kk][tn * 4];
      float a[4] = {av.x, av.y, av.z, av.w};
      float w[4] = {wv.x, wv.y, wv.z, wv.w};
#pragma unroll
      for (int ii = 0; ii < 4; ++ii)
#pragma unroll
        for (int jj = 0; jj < 4; ++jj) acc[ii][jj] += a[ii] * w[jj];
    }
    __syncthreads();
  }
#pragma unroll
  for (int ii = 0; ii < 4; ++ii) {
    int m = m0 + tm * 4 + ii;
    int b = m / S, s = m - b * S;
#pragma unroll
    for (int jj = 0; jj < 4; ++jj) {
      int n = n0 + tn * 4 + jj;
      if (n < P) keys[(size_t)m * P + n] = f2bf(acc[ii][jj] + bk[n]);
      else {
        int p = n - P;
        valuesT[((size_t)b * P + p) * S + s] = f2bf(acc[ii][jj] + bv[p]);
      }
    }
  }
}

// ---------------- context0 = mean over S of values (coherent ctx out) ----------------
__global__ void ctx0_mean(const unsigned short* __restrict__ valuesT,
                          unsigned short* __restrict__ ch,
                          unsigned short* __restrict__ cl) {
  int b = blockIdx.x, p = threadIdx.x;
  const uint4* vp = (const uint4*)(valuesT + ((size_t)b * P + p) * S);
  float acc = 0.0f;
#pragma unroll 10
  for (int i = 0; i < S / 8; ++i) {
    uint4 u = vp[i];
    acc += bf2f((unsigned short)(u.x & 0xffff)) + bf2f((unsigned short)(u.x >> 16));
    acc += bf2f((unsigned short)(u.y & 0xffff)) + bf2f((unsigned short)(u.y >> 16));
    acc += bf2f((unsigned short)(u.z & 0xffff)) + bf2f((unsigned short)(u.z >> 16));
    acc += bf2f((unsigned short)(u.w & 0xffff)) + bf2f((unsigned short)(u.w >> 16));
  }
  float m = acc * (1.0f / (float)S);
  unsigned short hb = f2bf(m);
  ch[b * P + p] = hb;
  cl[b * P + p] = f2bf(m - bf2f(hb));
}

// ---------------- persistent cooperative decoder ----------------
struct DecParams {
  const unsigned short *W1h, *W1l, *W2h, *W2l;
  const float *b1r, *b2r, *EmbW1;
  const int *y, *lens;
  const float *Wq, *bq, *emb, *b_out;
  const unsigned short *keys, *valuesT;
  unsigned short *h1a_h, *h1a_l, *h1b_h, *h1b_l;
  unsigned short *h2a_h, *h2a_l, *h2b_h, *h2b_l;
  float *c1, *c2;                 // transposed: [h][b] (block-private, normal cached)
  unsigned short *ctxh, *ctxlo;
  float *out;
  unsigned *flags, *gen;
};

// Fence-free barrier: all cross-block data moves via device-coherent (agent-scope
// atomic) loads/stores, so no L2 writeback/invalidate is required. __syncthreads
// drains vmcnt (HIP emits s_waitcnt vmcnt(0) before s_barrier), so every thread's
// coherent stores have reached the coherence point before the flag goes up.
__device__ __forceinline__ void gsync(unsigned* flags, unsigned* gen, unsigned expect) {
  __syncthreads();
  if (threadIdx.x == 0)
    __hip_atomic_store(&flags[blockIdx.x], expect, __ATOMIC_RELAXED,
                       __HIP_MEMORY_SCOPE_AGENT);
  if (blockIdx.x == 0) {
    if (threadIdx.x < NBLK) {
      while (__hip_atomic_load(&flags[threadIdx.x], __ATOMIC_RELAXED,
                               __HIP_MEMORY_SCOPE_AGENT) < expect)
        __builtin_amdgcn_s_sleep(1);
    }
    __syncthreads();
    if (threadIdx.x == 0)
      __hip_atomic_store(gen, expect, __ATOMIC_RELAXED, __HIP_MEMORY_SCOPE_AGENT);
  } else {
    if (threadIdx.x == 0) {
      while (__hip_atomic_load(gen, __ATOMIC_RELAXED,
                               __HIP_MEMORY_SCOPE_AGENT) < expect)
        __builtin_amdgcn_s_sleep(1);
    }
  }
  __syncthreads();
}

__global__ __launch_bounds__(NTHR, 1) void decoder_loop(DecParams p) {
  __shared__ unsigned short W1s[2][16][648];     // 41,472 B : W1 slice hi/lo
  __shared__ int tokl[2][B];                     // 1 KB
  __shared__ unsigned short hsth[B][4];          // 1 KB : pack staging
  __shared__ unsigned short hstl[B][4];          // 1 KB
  __shared__ union {
    float GtA[B][17];                            // 8,704 B (phase A)
    float GtB[4][32][17];                        // 8,704 B (phase B)
    struct { float h2f[H2]; float qv[P]; float sc[S]; float red[8];
             float cpart[4][P]; float ctxf[P]; } c;
  } u;

  const int tid = threadIdx.x;
  const int g = blockIdx.x;                      // 0..127
  const int n0 = g * 16;                         // lstm1 n'-tile
  const int n20 = (g >> 2) * 16;                 // lstm2 n-tile
  const int b20 = (g & 3) * 32;                  // lstm2 b-tile

  // ---- stage W1 slice to LDS (rows n0..n0+15, hi+lo) ----
  for (int i = tid; i < 16 * 80; i += NTHR) {
    int r = i / 80, k8 = (i - r * 80) * 8;
    *(short8v*)&W1s[0][r][k8] = *(const short8v*)&p.W1h[(size_t)(n0 + r) * K1R + k8];
    *(short8v*)&W1s[1][r][k8] = *(const short8v*)&p.W1l[(size_t)(n0 + r) * K1R + k8];
  }
  if (tid < B) { tokl[0][tid] = 0; tokl[1][tid] = 0; }   // t=0 -> SOS
  __syncthreads();

  const int lane = tid & 63, w8 = tid >> 6;
  const int lr = lane & 15, lq = lane >> 4;
  unsigned expect = 0;

  for (int t = 0; t < T; ++t) {
    const int cur = t & 1, nxt = cur ^ 1;
    const unsigned short* h1ph = cur ? p.h1b_h : p.h1a_h;
    const unsigned short* h1pl = cur ? p.h1b_l : p.h1a_l;
    unsigned short* h1nh = cur ? p.h1a_h : p.h1b_h;
    unsigned short* h1nl = cur ? p.h1a_l : p.h1b_l;
    const unsigned short* h2ph = cur ? p.h2b_h : p.h2a_h;
    const unsigned short* h2pl = cur ? p.h2b_l : p.h2a_l;
    unsigned short* h2nh = cur ? p.h2a_h : p.h2b_h;
    unsigned short* h2nl = cur ? p.h2a_l : p.h2b_l;

    // ================= Phase A : LSTM1 =================
    {
      const int brow = w8 * 16 + lr;             // this wave's b rows
      f32x4 acc0 = {0.f, 0.f, 0.f, 0.f};
      f32x4 acc1 = {0.f, 0.f, 0.f, 0.f};
#pragma unroll
      for (int cc = 0; cc < 4; ++cc) {           // ctx region, k 0..128
        const int ko = cc * 32 + lq * 8;
        short8v ah = load_coh16(p.ctxh + brow * P + ko);
        short8v al = load_coh16(p.ctxlo + brow * P + ko);
        short8v bh = *(const short8v*)&W1s[0][lr][ko];
        short8v bl = *(const short8v*)&W1s[1][lr][ko];
        if (cc & 1) { acc1 = MFMA16(ah, bh, acc1); acc1 = MFMA16(ah, bl, acc1); acc1 = MFMA16(al, bh, acc1); }
        else        { acc0 = MFMA16(ah, bh, acc0); acc0 = MFMA16(ah, bl, acc0); acc0 = MFMA16(al, bh, acc0); }
      }
#pragma unroll
      for (int cc = 0; cc < 16; ++cc) {          // h1 region, k 0..512
        const int ko = cc * 32 + lq * 8;
        short8v ah = load_coh16(h1ph + brow * H1 + ko);
        short8v al = load_coh16(h1pl + brow * H1 + ko);
        short8v bh = *(const short8v*)&W1s[0][lr][P + ko];
        short8v bl = *(const short8v*)&W1s[1][lr][P + ko];
        if (cc & 1) { acc1 = MFMA16(ah, bh, acc1); acc1 = MFMA16(ah, bl, acc1); acc1 = MFMA16(al, bh, acc1); }
        else        { acc0 = MFMA16(ah, bh, acc0); acc0 = MFMA16(ah, bl, acc0); acc0 = MFMA16(al, bh, acc0); }
      }
#pragma unroll
      for (int r = 0; r < 4; ++r)
        u.GtA[w8 * 16 + lq * 4 + r][lr] = acc0[r] + acc1[r];
      __syncthreads();
      // cell update: thread -> (b = tid&127, hl = tid>>7)
      {
        const int b = tid & 127, hl = tid >> 7;
        const int hg = g * 4 + hl;
        const int j = 4 * hl;
        const float4 e4 = *(const float4*)&p.EmbW1[(size_t)tokl[cur][b] * N1 + n0 + j];
        const float4 b4 = *(const float4*)&p.b1r[n0 + j];
        float gi = u.GtA[b][j + 0] + e4.x + b4.x;
        float gf = u.GtA[b][j + 1] + e4.y + b4.y;
        float gg = u.GtA[b][j + 2] + e4.z + b4.z;
        float go = u.GtA[b][j + 3] + e4.w + b4.w;
        float ii = sigmoidf_(gi), ff = sigmoidf_(gf), tg = tanhf(gg), oo = sigmoidf_(go);
        float cn = ff * p.c1[hg * B + b] + ii * tg;     // c1 transposed [h][b], block-private
        p.c1[hg * B + b] = cn;
        float hn = oo * tanhf(cn);
        unsigned short hb = f2bf(hn);
        hsth[b][hl] = hb;
        hstl[b][hl] = f2bf(hn - bf2f(hb));
      }
      __syncthreads();
      // packed coherent h1 writes: thread b writes 4 h as one u64 (hi + lo)
      if (tid < B) {
        astore64(&h1nh[tid * H1 + g * 4], pack4us(hsth[tid]));
        astore64(&h1nl[tid * H1 + g * 4], pack4us(hstl[tid]));
      } else if (tid >= 256 && tid < 256 + B && t + 1 < T) {
        tokl[nxt][tid - 256] = p.y[(tid - 256) * T + (t + 1)];
      }
    }
    gsync(p.flags, p.gen, ++expect);

    // ================= Phase B : LSTM2 =================
    {
      const int mw = w8 & 1, kw = w8 >> 1;       // 2 m-tiles x 4 k-slices
      const int brow = b20 + mw * 16 + lr;
      const int nrow = n20 + lr;
      const unsigned short* wph = p.W2h + (size_t)nrow * K2;
      const unsigned short* wpl = p.W2l + (size_t)nrow * K2;
      f32x4 acc = {0.f, 0.f, 0.f, 0.f};
      if (kw < 3) {
#pragma unroll
        for (int cc = 0; cc < 5; ++cc) {
          const int ko = kw * 160 + cc * 32 + lq * 8;   // h1 region
          short8v ah = load_coh16(h1nh + brow * H1 + ko);
          short8v al = load_coh16(h1nl + brow * H1 + ko);
          short8v bh = *(const short8v*)(wph + ko);
          short8v bl = *(const short8v*)(wpl + ko);
          acc = MFMA16(ah, bh, acc); acc = MFMA16(ah, bl, acc); acc = MFMA16(al, bh, acc);
        }
      } else {
        {
          const int ko = 480 + lq * 8;                  // h1 tail
          short8v ah = load_coh16(h1nh + brow * H1 + ko);
          short8v al = load_coh16(h1nl + brow * H1 + ko);
          short8v bh = *(const short8v*)(wph + ko);
          short8v bl = *(const short8v*)(wpl + ko);
          acc = MFMA16(ah, bh, acc); acc = MFMA16(ah, bl, acc); acc = MFMA16(al, bh, acc);
        }
#pragma unroll
        for (int cc = 0; cc < 4; ++cc) {
          const int koff = cc * 32 + lq * 8;            // h2 region
          short8v ah = load_coh16(h2ph + brow * H2 + koff);
          short8v al = load_coh16(h2pl + brow * H2 + koff);
          short8v bh = *(const short8v*)(wph + H1 + koff);
          short8v bl = *(const short8v*)(wpl + H1 + koff);
          acc = MFMA16(ah, bh, acc); acc = MFMA16(ah, bl, acc); acc = MFMA16(al, bh, acc);
        }
      }
#pragma unroll
      for (int r = 0; r < 4; ++r) u.GtB[kw][mw * 16 + lq * 4 + r][lr] = acc[r];
      __syncthreads();
      {
        const int bl_ = tid >> 4, j = tid & 15;
        float s = u.GtB[0][bl_][j] + u.GtB[1][bl_][j] + u.GtB[2][bl_][j] +
                  u.GtB[3][bl_][j] + p.b2r[n20 + j];
        __syncthreads();
        u.GtB[0][bl_][j] = s;
      }
      __syncthreads();
      if (tid < 128) {
        const int bl_ = tid & 31, hl = tid >> 5;
        const int b = b20 + bl_;
        const int hg = (g >> 2) * 4 + hl;
        const int j = 4 * hl;
        float ii = sigmoidf_(u.GtB[0][bl_][j + 0]);
        float ff = sigmoidf_(u.GtB[0][bl_][j + 1]);
        float tg = tanhf(u.GtB[0][bl_][j + 2]);
        float oo = sigmoidf_(u.GtB[0][bl_][j + 3]);
        float cn = ff * p.c2[hg * B + b] + ii * tg;     // c2 [h][b], block-private
        p.c2[hg * B + b] = cn;
        float hn = oo * tanhf(cn);
        unsigned short hb = f2bf(hn);
        hsth[bl_][hl] = hb;
        hstl[bl_][hl] = f2bf(hn - bf2f(hb));
      }
      __syncthreads();
      // packed coherent h2 writes: thread j<32 writes its b's 4 consecutive hg as u64
      if (tid < 32) {
        const int b = b20 + tid;
        astore64(&h2nh[b * H2 + (g >> 2) * 4], pack4us(hsth[tid]));
        astore64(&h2nl[b * H2 + (g >> 2) * 4], pack4us(hstl[tid]));
      }
    }
    gsync(p.flags, p.gen, ++expect);

    // ================= Phase C : attention + logits (block = batch row) =================
    {
      const int b = g;
      if (tid < 32) {
        u64s4 hh, ll;
        hh.u = aload64(&h2nh[b * H2 + 4 * tid]);
        ll.u = aload64(&h2nl[b * H2 + 4 * tid]);
#pragma unroll
        for (int j = 0; j < 4; ++j)
          u.c.h2f[4 * tid + j] = bf2f((unsigned short)hh.s[j]) + bf2f((unsigned short)ll.s[j]);
      }
      __syncthreads();
      if (tid < P) {
        float a = p.bq[tid];
        const float* wr = &p.Wq[tid * H2];
#pragma unroll 8
        for (int k = 0; k < H2; k += 4) {
          float4 wv = *(const float4*)&wr[k];
          a += wv.x * u.c.h2f[k] + wv.y * u.c.h2f[k + 1] +
               wv.z * u.c.h2f[k + 2] + wv.w * u.c.h2f[k + 3];
        }
        u.c.qv[tid] = a;
      }
      __syncthreads();
      const float scale = 0.08838834764831845f;
      const int len = p.lens[b];
      if (tid < S) {
        const uint4* kr = (const uint4*)&p.keys[((size_t)b * S + tid) * P];
        float a = 0.0f;
#pragma unroll
        for (int k8 = 0; k8 < 16; ++k8) {
          uint4 uu = kr[k8];
          const float* q8 = &u.c.qv[k8 * 8];
          a += __uint_as_float(uu.x << 16) * q8[0] + __uint_as_float(uu.x & 0xffff0000u) * q8[1];
          a += __uint_as_float(uu.y << 16) * q8[2] + __uint_as_float(uu.y & 0xffff0000u) * q8[3];
          a += __uint_as_float(uu.z << 16) * q8[4] + __uint_as_float(uu.z & 0xffff0000u) * q8[5];
          a += __uint_as_float(uu.w << 16) * q8[6] + __uint_as_float(uu.w & 0xffff0000u) * q8[7];
        }
        a *= scale;
        if (tid >= len) a = -1e9f;
        u.c.sc[tid] = a;
      }
      __syncthreads();
      float m_ = (tid < S) ? u.c.sc[tid] : -INFINITY;
#pragma unroll
      for (int off = 32; off > 0; off >>= 1) m_ = fmaxf(m_, __shfl_xor(m_, off));
      if (lane == 0) u.c.red[w8] = m_;
      __syncthreads();
      float mx = u.c.red[0];
#pragma unroll
      for (int i = 1; i < 8; ++i) mx = fmaxf(mx, u.c.red[i]);
      __syncthreads();
      float e_ = 0.0f;
      if (tid < S) {
        e_ = expf(u.c.sc[tid] - mx);
        u.c.sc[tid] = e_;
      }
      float s_ = e_;
#pragma unroll
      for (int off = 32; off > 0; off >>= 1) s_ += __shfl_xor(s_, off);
      if (lane == 0) u.c.red[w8] = s_;
      __syncthreads();
      float ssum = u.c.red[0] + u.c.red[1] + u.c.red[2] + u.c.red[3] +
                   u.c.red[4] + u.c.red[5] + u.c.red[6] + u.c.red[7];
      const float inv = 1.0f / ssum;
      if (tid < S) {
        float wv = u.c.sc[tid] * inv;
        u.c.sc[tid] = wv;
        if (b == 0) p.out[PRED_SIZE + (size_t)t * S + tid] = wv;
      }
      __syncthreads();
      {
        const int qd = tid >> 7, pp = tid & 127;
        const uint2* vp = (const uint2*)(p.valuesT + ((size_t)b * P + pp) * S + qd * 100);
        const float* sp = &u.c.sc[qd * 100];
        float a = 0.0f;
#pragma unroll
        for (int i = 0; i < 25; ++i) {
          uint2 uu = vp[i];
          const float* s4 = &sp[i * 4];
          a += __uint_as_float(uu.x << 16) * s4[0] + __uint_as_float(uu.x & 0xffff0000u) * s4[1];
          a += __uint_as_float(uu.y << 16) * s4[2] + __uint_as_float(uu.y & 0xffff0000u) * s4[3];
        }
        u.c.cpart[qd][pp] = a;
      }
      __syncthreads();
      if (tid < P) {
        float c = u.c.cpart[0][tid] + u.c.cpart[1][tid] + u.c.cpart[2][tid] + u.c.cpart[3][tid];
        u.c.ctxf[tid] = c;
      }
      __syncthreads();
      // packed coherent ctx writes: thread j<32 packs 4 consecutive p (hi and lo)
      if (tid < 32) {
        unsigned short hb[4], lb[4];
#pragma unroll
        for (int j = 0; j < 4; ++j) {
          float c = u.c.ctxf[4 * tid + j];
          hb[j] = f2bf(c);
          lb[j] = f2bf(c - bf2f(hb[j]));
        }
        astore64(&p.ctxh[b * P + 4 * tid], pack4us(hb));
        astore64(&p.ctxlo[b * P + 4 * tid], pack4us(lb));
      }
      __syncthreads();
      {
        const int g3 = tid >> 4, l4 = tid & 15;
        if (g3 < V) {
          float a = 0.0f;
          const float* er = &p.emb[g3 * EMB + l4 * 16];
#pragma unroll
          for (int i = 0; i < 4; ++i) {
            float4 e4 = *(const float4*)&er[i * 4];
            int k0 = l4 * 16 + i * 4;
            float x0 = (k0 + 0 < P) ? u.c.ctxf[k0 + 0] : u.c.h2f[k0 + 0 - P];
            float x1 = (k0 + 1 < P) ? u.c.ctxf[k0 + 1] : u.c.h2f[k0 + 1 - P];
            float x2 = (k0 + 2 < P) ? u.c.ctxf[k0 + 2] : u.c.h2f[k0 + 2 - P];
            float x3 = (k0 + 3 < P) ? u.c.ctxf[k0 + 3] : u.c.h2f[k0 + 3 - P];
            a += e4.x * x0 + e4.y * x1 + e4.z * x2 + e4.w * x3;
          }
          a += __shfl_xor(a, 8);
          a += __shfl_xor(a, 4);
          a += __shfl_xor(a, 2);
          a += __shfl_xor(a, 1);
          if (l4 == 0) p.out[((size_t)b * V + g3) * T + t] = a + p.b_out[g3];
        }
      }
    }
    gsync(p.flags, p.gen, ++expect);
  }
}

extern "C" void kernel_launch(void* const* d_in, const int* in_sizes, int n_in,
                              void* d_out, int out_size, void* d_ws, size_t ws_size,
                              hipStream_t stream) {
  const float* enc  = (const float*)d_in[0];
  const int*   lens = (const int*)d_in[1];
  const int*   y    = (const int*)d_in[2];
  const float* emb  = (const float*)d_in[3];
  const float* Wih1 = (const float*)d_in[4];
  const float* Whh1 = (const float*)d_in[5];
  const float* bih1 = (const float*)d_in[6];
  const float* bhh1 = (const float*)d_in[7];
  const float* Wih2 = (const float*)d_in[8];
  const float* Whh2 = (const float*)d_in[9];
  const float* bih2 = (const float*)d_in[10];
  const float* bhh2 = (const float*)d_in[11];
  const float* Wk   = (const float*)d_in[12];
  const float* bk   = (const float*)d_in[13];
  const float* Wv   = (const float*)d_in[14];
  const float* bv   = (const float*)d_in[15];
  const float* Wq   = (const float*)d_in[16];
  const float* bq   = (const float*)d_in[17];
  const float* b_out= (const float*)d_in[18];
  float* out = (float*)d_out;

  // ---- workspace layout: zeroed region first ----
  char* cur = (char*)d_ws;
  unsigned* flags = (unsigned*)cur;             cur += 1024;  // flags[128] + gen
  unsigned* gen = flags + 128;
  float* c1 = (float*)cur;                      cur += (size_t)B * H1 * 4;  // [h][b]
  float* c2 = (float*)cur;                      cur += (size_t)B * H2 * 4;  // [h][b]
  unsigned short* h1a_h = (unsigned short*)cur; cur += (size_t)B * H1 * 2;
  unsigned short* h1a_l = (unsigned short*)cur; cur += (size_t)B * H1 * 2;
  unsigned short* h2a_h = (unsigned short*)cur; cur += (size_t)B * H2 * 2;
  unsigned short* h2a_l = (unsigned short*)cur; cur += (size_t)B * H2 * 2;
  const size_t zero_bytes = (size_t)cur - (size_t)d_ws;
  unsigned short* h1b_h = (unsigned short*)cur; cur += (size_t)B * H1 * 2;
  unsigned short* h1b_l = (unsigned short*)cur; cur += (size_t)B * H1 * 2;
  unsigned short* h2b_h = (unsigned short*)cur; cur += (size_t)B * H2 * 2;
  unsigned short* h2b_l = (unsigned short*)cur; cur += (size_t)B * H2 * 2;
  unsigned short* ctxh  = (unsigned short*)cur; cur += (size_t)B * P * 2;
  unsigned short* ctxlo = (unsigned short*)cur; cur += (size_t)B * P * 2;
  float* b1r = (float*)cur;                     cur += (size_t)N1 * 4;
  float* b2r = (float*)cur;                     cur += (size_t)N2 * 4;
  float* EmbW1 = (float*)cur;                   cur += (size_t)V * N1 * 4;
  unsigned short* keys    = (unsigned short*)cur; cur += (size_t)B * S * P * 2;
  unsigned short* valuesT = (unsigned short*)cur; cur += (size_t)B * S * P * 2;
  unsigned short* W1h = (unsigned short*)cur;   cur += (size_t)N1 * K1R * 2;
  unsigned short* W1l = (unsigned short*)cur;   cur += (size_t)N1 * K1R * 2;
  unsigned short* W2h = (unsigned short*)cur;   cur += (size_t)N2 * K2 * 2;
  unsigned short* W2l = (unsigned short*)cur;   cur += (size_t)N2 * K2 * 2;

  hipMemsetAsync(d_ws, 0, zero_bytes, stream);

  prep_weights<<<2048, 256, 0, stream>>>(Wih1, Whh1, bih1, bhh1, Wih2, Whh2,
                                         bih2, bhh2, W1h, W1l, W2h, W2l, b1r, b2r);
  emb_w1<<<(V * N1 + 255) / 256, 256, 0, stream>>>(emb, Wih1, EmbW1);
  kv_gemm<<<dim3((B * S) / 64, 4), 256, 0, stream>>>(enc, Wk, bk, Wv, bv, keys, valuesT);
  ctx0_mean<<<B, P, 0, stream>>>(valuesT, ctxh, ctxlo);

  DecParams prm;
  prm.W1h = W1h; prm.W1l = W1l; prm.W2h = W2h; prm.W2l = W2l;
  prm.b1r = b1r; prm.b2r = b2r; prm.EmbW1 = EmbW1;
  prm.y = y; prm.lens = lens;
  prm.Wq = Wq; prm.bq = bq; prm.emb = emb; prm.b_out = b_out;
  prm.keys = keys; prm.valuesT = valuesT;
  prm.h1a_h = h1a_h; prm.h1a_l = h1a_l; prm.h1b_h = h1b_h; prm.h1b_l = h1b_l;
  prm.h2a_h = h2a_h; prm.h2a_l = h2a_l; prm.h2b_h = h2b_h; prm.h2b_l = h2b_l;
  prm.c1 = c1; prm.c2 = c2;
  prm.ctxh = ctxh; prm.ctxlo = ctxlo;
  prm.out = out;
  prm.flags = flags; prm.gen = gen;

  void* kargs[] = { &prm };
  hipLaunchCooperativeKernel((const void*)decoder_loop, dim3(NBLK), dim3(NTHR),
                             kargs, 0, stream);
}

// Round 9
// 11160.608 us; speedup vs baseline: 1.2459x; 1.2459x over previous
//
#include <hip/hip_runtime.h>
#include <math.h>

#define B 128
#define S 400
#define EENC 512
#define T 300
#define V 30
#define EMB 256
#define H1 512
#define H2 128
#define P 128
#define XD (P + EMB)   // 384
#define K1R (P + H1)   // 640 : LSTM1 serial reduction (ctx + h1); emb precomputed
#define K2 (H1 + H2)   // 640 : LSTM2 reduction
#define N1 (4 * H1)    // 2048
#define N2 (4 * H2)    // 512
#define PRED_SIZE (B * V * T)
#define NBLK 128
#define NTHR 512
#define RING 64        // rotation slots; full L2 invalidate every 32 steps

typedef __attribute__((ext_vector_type(8))) short short8v;
typedef __attribute__((ext_vector_type(4))) short short4v;
typedef __attribute__((ext_vector_type(4))) float f32x4;

#define MFMA16(a, b, c) __builtin_amdgcn_mfma_f32_16x16x32_bf16((a), (b), (c), 0, 0, 0)

__device__ __forceinline__ float sigmoidf_(float x) { return 1.0f / (1.0f + expf(-x)); }

__device__ __forceinline__ unsigned short f2bf(float x) {
  unsigned int u = __float_as_uint(x);
  u = (u + 0x7FFFu + ((u >> 16) & 1u)) >> 16;
  return (unsigned short)u;
}
__device__ __forceinline__ float bf2f(unsigned short s) {
  return __uint_as_float(((unsigned int)s) << 16);
}

// write-through to coherence point (cross-XCD visible without L2 flush)
__device__ __forceinline__ void astore64(void* p, unsigned long long v) {
  __hip_atomic_store((unsigned long long*)p, v, __ATOMIC_RELAXED,
                     __HIP_MEMORY_SCOPE_AGENT);
}
__device__ __forceinline__ unsigned long long pack4us(const unsigned short* s) {
  return (unsigned long long)s[0] | ((unsigned long long)s[1] << 16) |
         ((unsigned long long)s[2] << 32) | ((unsigned long long)s[3] << 48);
}
union u64s4 { unsigned long long u; short4v s; };

// ---------------- one-time weight prep ----------------
__global__ void prep_weights(
    const float* __restrict__ Wih1, const float* __restrict__ Whh1,
    const float* __restrict__ bih1, const float* __restrict__ bhh1,
    const float* __restrict__ Wih2, const float* __restrict__ Whh2,
    const float* __restrict__ bih2, const float* __restrict__ bhh2,
    unsigned short* __restrict__ W1h, unsigned short* __restrict__ W1l,
    unsigned short* __restrict__ W2h, unsigned short* __restrict__ W2l,
    float* __restrict__ b1r, float* __restrict__ b2r) {
  const int T1 = N1 * K1R;
  const int T2 = N2 * K2;
  const int TOT = T1 + T2 + N1 + N2;
  for (int idx = blockIdx.x * blockDim.x + threadIdx.x; idx < TOT;
       idx += gridDim.x * blockDim.x) {
    if (idx < T1) {
      int np = idx / K1R, k = idx - np * K1R;
      int h = np >> 2, s = np & 3;
      int no = s * H1 + h;
      float v = (k < P) ? Wih1[no * XD + k] : Whh1[no * H1 + (k - P)];
      unsigned short hb = f2bf(v);
      W1h[idx] = hb;
      W1l[idx] = f2bf(v - bf2f(hb));
    } else if (idx < T1 + T2) {
      int i2 = idx - T1;
      int np = i2 / K2, k = i2 - np * K2;
      int h = np >> 2, s = np & 3;
      int no = s * H2 + h;
      float v = (k < H1) ? Wih2[no * H1 + k] : Whh2[no * H2 + (k - H1)];
      unsigned short hb = f2bf(v);
      W2h[i2] = hb;
      W2l[i2] = f2bf(v - bf2f(hb));
    } else if (idx < T1 + T2 + N1) {
      int np = idx - T1 - T2;
      int h = np >> 2, s = np & 3;
      b1r[np] = bih1[s * H1 + h] + bhh1[s * H1 + h];
    } else {
      int np = idx - T1 - T2 - N1;
      int h = np >> 2, s = np & 3;
      b2r[np] = bih2[s * H2 + h] + bhh2[s * H2 + h];
    }
  }
}

// ---------------- EmbW1[v][n'] = emb[v] . Wih1_embcols[n'] ----------------
__global__ __launch_bounds__(256) void emb_w1(
    const float* __restrict__ emb, const float* __restrict__ Wih1,
    float* __restrict__ EmbW1) {
  int idx = blockIdx.x * 256 + threadIdx.x;
  if (idx >= V * N1) return;
  int v = idx >> 11;
  int np = idx & (N1 - 1);
  int h = np >> 2, s = np & 3;
  int no = s * H1 + h;
  const float* er = emb + v * EMB;
  const float* wr = Wih1 + no * XD + P;
  float a = 0.0f;
#pragma unroll 8
  for (int k = 0; k < EMB; k += 4) {
    float4 e4 = *(const float4*)&er[k];
    float4 w4 = *(const float4*)&wr[k];
    a += e4.x * w4.x + e4.y * w4.y + e4.z * w4.z + e4.w * w4.w;
  }
  EmbW1[idx] = a;
}

// ---------------- keys/values precompute GEMM ----------------
__global__ __launch_bounds__(256) void kv_gemm(
    const float* __restrict__ enc, const float* __restrict__ Wk,
    const float* __restrict__ bk, const float* __restrict__ Wv,
    const float* __restrict__ bv, unsigned short* __restrict__ keys,
    unsigned short* __restrict__ valuesT) {
  __shared__ float As[32][68];
  __shared__ float Ws[32][68];
  const int tid = threadIdx.x;
  const int m0 = blockIdx.x * 64;
  const int n0 = blockIdx.y * 64;
  const int tm = tid & 15, tn = tid >> 4;
  float acc[4][4] = {};
  for (int kc = 0; kc < EENC; kc += 32) {
    for (int i = tid; i < 64 * 32; i += 256) {
      int mm = i >> 5, kk = i & 31;
      As[kk][mm] = enc[(size_t)(m0 + mm) * EENC + kc + kk];
    }
    for (int i = tid; i < 64 * 32; i += 256) {
      int nn = i >> 5, kk = i & 31;
      int n = n0 + nn;
      Ws[kk][nn] = (n < P) ? Wk[n * EENC + kc + kk] : Wv[(n - P) * EENC + kc + kk];
    }
    __syncthreads();
#pragma unroll
    for (int kk = 0; kk < 32; ++kk) {
      float4 av = *(const float4*)&As[kk][tm * 4];
      float4 wv = *(const float4*)&Ws[kk][tn * 4];
      float a[4] = {av.x, av.y, av.z, av.w};
      float w[4] = {wv.x, wv.y, wv.z, wv.w};
#pragma unroll
      for (int ii = 0; ii < 4; ++ii)
#pragma unroll
        for (int jj = 0; jj < 4; ++jj) acc[ii][jj] += a[ii] * w[jj];
    }
    __syncthreads();
  }
#pragma unroll
  for (int ii = 0; ii < 4; ++ii) {
    int m = m0 + tm * 4 + ii;
    int b = m / S, s = m - b * S;
#pragma unroll
    for (int jj = 0; jj < 4; ++jj) {
      int n = n0 + tn * 4 + jj;
      if (n < P) keys[(size_t)m * P + n] = f2bf(acc[ii][jj] + bk[n]);
      else {
        int p = n - P;
        valuesT[((size_t)b * P + p) * S + s] = f2bf(acc[ii][jj] + bv[p]);
      }
    }
  }
}

// ---------------- context0 = mean over S of values (writes ctx ring slot 0) ----------------
__global__ void ctx0_mean(const unsigned short* __restrict__ valuesT,
                          unsigned short* __restrict__ ch,
                          unsigned short* __restrict__ cl) {
  int b = blockIdx.x, p = threadIdx.x;
  const uint4* vp = (const uint4*)(valuesT + ((size_t)b * P + p) * S);
  float acc = 0.0f;
#pragma unroll 10
  for (int i = 0; i < S / 8; ++i) {
    uint4 u = vp[i];
    acc += bf2f((unsigned short)(u.x & 0xffff)) + bf2f((unsigned short)(u.x >> 16));
    acc += bf2f((unsigned short)(u.y & 0xffff)) + bf2f((unsigned short)(u.y >> 16));
    acc += bf2f((unsigned short)(u.z & 0xffff)) + bf2f((unsigned short)(u.z >> 16));
    acc += bf2f((unsigned short)(u.w & 0xffff)) + bf2f((unsigned short)(u.w >> 16));
  }
  float m = acc * (1.0f / (float)S);
  unsigned short hb = f2bf(m);
  ch[b * P + p] = hb;
  cl[b * P + p] = f2bf(m - bf2f(hb));
}

// ---------------- persistent cooperative decoder ----------------
struct DecParams {
  const unsigned short *W1h, *W1l, *W2h, *W2l;
  const float *b1r, *b2r, *EmbW1;
  const int *y, *lens;
  const float *Wq, *bq, *emb, *b_out;
  const unsigned short *keys, *valuesT;
  unsigned short *h1h, *h1l;      // ring: RING slots of [B][H1]
  unsigned short *h2h, *h2l;      // ring: RING slots of [B][H2]
  unsigned short *cth, *ctl;      // ring: RING slots of [B][P]
  float *c1, *c2;                 // block-private, [h][b]
  float *out;
  unsigned *flags, *gen;
};

// Fence-free barrier. Cross-block data: written write-through (agent atomics),
// read via plain cached loads of ring addresses that are L2-cold by construction.
// Every 32 steps (inv=true) an acquire fence invalidates clean L1/L2 lines so no
// stale copy can survive until a ring slot's reuse 63 steps later.
__device__ __forceinline__ void gsync(unsigned* flags, unsigned* gen,
                                      unsigned expect, bool inv) {
  __syncthreads();
  if (threadIdx.x == 0)
    __hip_atomic_store(&flags[blockIdx.x], expect, __ATOMIC_RELAXED,
                       __HIP_MEMORY_SCOPE_AGENT);
  if (blockIdx.x == 0) {
    if (threadIdx.x < NBLK) {
      while (__hip_atomic_load(&flags[threadIdx.x], __ATOMIC_RELAXED,
                               __HIP_MEMORY_SCOPE_AGENT) < expect)
        __builtin_amdgcn_s_sleep(1);
    }
    __syncthreads();
    if (threadIdx.x == 0) {
      __hip_atomic_store(gen, expect, __ATOMIC_RELAXED, __HIP_MEMORY_SCOPE_AGENT);
      if (inv) __builtin_amdgcn_fence(__ATOMIC_ACQUIRE, "agent");
    }
  } else {
    if (threadIdx.x == 0) {
      while (__hip_atomic_load(gen, __ATOMIC_RELAXED,
                               __HIP_MEMORY_SCOPE_AGENT) < expect)
        __builtin_amdgcn_s_sleep(1);
      if (inv) __builtin_amdgcn_fence(__ATOMIC_ACQUIRE, "agent");
    }
  }
  __syncthreads();
}

__global__ __launch_bounds__(NTHR, 1) void decoder_loop(DecParams p) {
  __shared__ unsigned short W1s[2][16][648];     // 41,472 B : W1 slice hi/lo
  __shared__ int tokl[2][B];                     // 1 KB
  __shared__ unsigned short hsth[B][4];          // 1 KB : pack staging
  __shared__ unsigned short hstl[B][4];          // 1 KB
  __shared__ union {
    float GtA[B][17];                            // 8,704 B (phase A)
    float GtB[4][32][17];                        // 8,704 B (phase B)
    struct { float h2f[H2]; float qv[P]; float sc[S]; float red[8];
             float cpart[4][P]; float ctxf[P]; } c;
  } u;

  const int tid = threadIdx.x;
  const int g = blockIdx.x;                      // 0..127
  const int n0 = g * 16;                         // lstm1 n'-tile
  const int n20 = (g >> 2) * 16;                 // lstm2 n-tile
  const int b20 = (g & 3) * 32;                  // lstm2 b-tile

  // ---- stage W1 slice to LDS (rows n0..n0+15, hi+lo) ----
  for (int i = tid; i < 16 * 80; i += NTHR) {
    int r = i / 80, k8 = (i - r * 80) * 8;
    *(short8v*)&W1s[0][r][k8] = *(const short8v*)&p.W1h[(size_t)(n0 + r) * K1R + k8];
    *(short8v*)&W1s[1][r][k8] = *(const short8v*)&p.W1l[(size_t)(n0 + r) * K1R + k8];
  }
  if (tid < B) { tokl[0][tid] = 0; tokl[1][tid] = 0; }   // t=0 -> SOS
  __syncthreads();

  const int lane = tid & 63, w8 = tid >> 6;
  const int lr = lane & 15, lq = lane >> 4;
  unsigned expect = 0;

  for (int t = 0; t < T; ++t) {
    const int cur = t & 1, nxt = cur ^ 1;
    const int sp = t & (RING - 1), sn = (t + 1) & (RING - 1);
    const unsigned short* h1ph = p.h1h + (size_t)sp * (B * H1);
    const unsigned short* h1pl = p.h1l + (size_t)sp * (B * H1);
    unsigned short* h1nh = p.h1h + (size_t)sn * (B * H1);
    unsigned short* h1nl = p.h1l + (size_t)sn * (B * H1);
    const unsigned short* h2ph = p.h2h + (size_t)sp * (B * H2);
    const unsigned short* h2pl = p.h2l + (size_t)sp * (B * H2);
    unsigned short* h2nh = p.h2h + (size_t)sn * (B * H2);
    unsigned short* h2nl = p.h2l + (size_t)sn * (B * H2);
    const unsigned short* ctph = p.cth + (size_t)sp * (B * P);
    const unsigned short* ctpl = p.ctl + (size_t)sp * (B * P);
    unsigned short* ctnh = p.cth + (size_t)sn * (B * P);
    unsigned short* ctnl = p.ctl + (size_t)sn * (B * P);

    // ================= Phase A : LSTM1 =================
    {
      const int brow = w8 * 16 + lr;             // this wave's b rows
      f32x4 acc0 = {0.f, 0.f, 0.f, 0.f};
      f32x4 acc1 = {0.f, 0.f, 0.f, 0.f};
#pragma unroll
      for (int cc = 0; cc < 4; ++cc) {           // ctx region, k 0..128
        const int ko = cc * 32 + lq * 8;
        short8v ah = *(const short8v*)(ctph + brow * P + ko);
        short8v al = *(const short8v*)(ctpl + brow * P + ko);
        short8v bh = *(const short8v*)&W1s[0][lr][ko];
        short8v bl = *(const short8v*)&W1s[1][lr][ko];
        if (cc & 1) { acc1 = MFMA16(ah, bh, acc1); acc1 = MFMA16(ah, bl, acc1); acc1 = MFMA16(al, bh, acc1); }
        else        { acc0 = MFMA16(ah, bh, acc0); acc0 = MFMA16(ah, bl, acc0); acc0 = MFMA16(al, bh, acc0); }
      }
#pragma unroll
      for (int cc = 0; cc < 16; ++cc) {          // h1 region, k 0..512
        const int ko = cc * 32 + lq * 8;
        short8v ah = *(const short8v*)(h1ph + brow * H1 + ko);
        short8v al = *(const short8v*)(h1pl + brow * H1 + ko);
        short8v bh = *(const short8v*)&W1s[0][lr][P + ko];
        short8v bl = *(const short8v*)&W1s[1][lr][P + ko];
        if (cc & 1) { acc1 = MFMA16(ah, bh, acc1); acc1 = MFMA16(ah, bl, acc1); acc1 = MFMA16(al, bh, acc1); }
        else        { acc0 = MFMA16(ah, bh, acc0); acc0 = MFMA16(ah, bl, acc0); acc0 = MFMA16(al, bh, acc0); }
      }
#pragma unroll
      for (int r = 0; r < 4; ++r)
        u.GtA[w8 * 16 + lq * 4 + r][lr] = acc0[r] + acc1[r];
      __syncthreads();
      // cell update: thread -> (b = tid&127, hl = tid>>7)
      {
        const int b = tid & 127, hl = tid >> 7;
        const int hg = g * 4 + hl;
        const int j = 4 * hl;
        const float4 e4 = *(const float4*)&p.EmbW1[(size_t)tokl[cur][b] * N1 + n0 + j];
        const float4 b4 = *(const float4*)&p.b1r[n0 + j];
        float gi = u.GtA[b][j + 0] + e4.x + b4.x;
        float gf = u.GtA[b][j + 1] + e4.y + b4.y;
        float gg = u.GtA[b][j + 2] + e4.z + b4.z;
        float go = u.GtA[b][j + 3] + e4.w + b4.w;
        float ii = sigmoidf_(gi), ff = sigmoidf_(gf), tg = tanhf(gg), oo = sigmoidf_(go);
        float cn = ff * p.c1[hg * B + b] + ii * tg;     // block-private
        p.c1[hg * B + b] = cn;
        float hn = oo * tanhf(cn);
        unsigned short hb = f2bf(hn);
        hsth[b][hl] = hb;
        hstl[b][hl] = f2bf(hn - bf2f(hb));
      }
      __syncthreads();
      // packed write-through h1 writes into ring slot sn
      if (tid < B) {
        astore64(&h1nh[tid * H1 + g * 4], pack4us(hsth[tid]));
        astore64(&h1nl[tid * H1 + g * 4], pack4us(hstl[tid]));
      } else if (tid >= 256 && tid < 256 + B && t + 1 < T) {
        tokl[nxt][tid - 256] = p.y[(tid - 256) * T + (t + 1)];
      }
    }
    gsync(p.flags, p.gen, ++expect, false);

    // ================= Phase B : LSTM2 =================
    {
      const int mw = w8 & 1, kw = w8 >> 1;       // 2 m-tiles x 4 k-slices
      const int brow = b20 + mw * 16 + lr;
      const int nrow = n20 + lr;
      const unsigned short* wph = p.W2h + (size_t)nrow * K2;
      const unsigned short* wpl = p.W2l + (size_t)nrow * K2;
      f32x4 acc = {0.f, 0.f, 0.f, 0.f};
      if (kw < 3) {
#pragma unroll
        for (int cc = 0; cc < 5; ++cc) {
          const int ko = kw * 160 + cc * 32 + lq * 8;   // h1 region
          short8v ah = *(const short8v*)(h1nh + brow * H1 + ko);
          short8v al = *(const short8v*)(h1nl + brow * H1 + ko);
          short8v bh = *(const short8v*)(wph + ko);
          short8v bl = *(const short8v*)(wpl + ko);
          acc = MFMA16(ah, bh, acc); acc = MFMA16(ah, bl, acc); acc = MFMA16(al, bh, acc);
        }
      } else {
        {
          const int ko = 480 + lq * 8;                  // h1 tail
          short8v ah = *(const short8v*)(h1nh + brow * H1 + ko);
          short8v al = *(const short8v*)(h1nl + brow * H1 + ko);
          short8v bh = *(const short8v*)(wph + ko);
          short8v bl = *(const short8v*)(wpl + ko);
          acc = MFMA16(ah, bh, acc); acc = MFMA16(ah, bl, acc); acc = MFMA16(al, bh, acc);
        }
#pragma unroll
        for (int cc = 0; cc < 4; ++cc) {
          const int koff = cc * 32 + lq * 8;            // h2 region
          short8v ah = *(const short8v*)(h2ph + brow * H2 + koff);
          short8v al = *(const short8v*)(h2pl + brow * H2 + koff);
          short8v bh = *(const short8v*)(wph + H1 + koff);
          short8v bl = *(const short8v*)(wpl + H1 + koff);
          acc = MFMA16(ah, bh, acc); acc = MFMA16(ah, bl, acc); acc = MFMA16(al, bh, acc);
        }
      }
#pragma unroll
      for (int r = 0; r < 4; ++r) u.GtB[kw][mw * 16 + lq * 4 + r][lr] = acc[r];
      __syncthreads();
      {
        const int bl_ = tid >> 4, j = tid & 15;
        float s = u.GtB[0][bl_][j] + u.GtB[1][bl_][j] + u.GtB[2][bl_][j] +
                  u.GtB[3][bl_][j] + p.b2r[n20 + j];
        __syncthreads();
        u.GtB[0][bl_][j] = s;
      }
      __syncthreads();
      if (tid < 128) {
        const int bl_ = tid & 31, hl = tid >> 5;
        const int b = b20 + bl_;
        const int hg = (g >> 2) * 4 + hl;
        const int j = 4 * hl;
        float ii = sigmoidf_(u.GtB[0][bl_][j + 0]);
        float ff = sigmoidf_(u.GtB[0][bl_][j + 1]);
        float tg = tanhf(u.GtB[0][bl_][j + 2]);
        float oo = sigmoidf_(u.GtB[0][bl_][j + 3]);
        float cn = ff * p.c2[hg * B + b] + ii * tg;     // block-private
        p.c2[hg * B + b] = cn;
        float hn = oo * tanhf(cn);
        unsigned short hb = f2bf(hn);
        hsth[bl_][hl] = hb;
        hstl[bl_][hl] = f2bf(hn - bf2f(hb));
      }
      __syncthreads();
      if (tid < 32) {
        const int b = b20 + tid;
        astore64(&h2nh[b * H2 + (g >> 2) * 4], pack4us(hsth[tid]));
        astore64(&h2nl[b * H2 + (g >> 2) * 4], pack4us(hstl[tid]));
      }
    }
    gsync(p.flags, p.gen, ++expect, false);

    // ================= Phase C : attention + logits (block = batch row) =================
    {
      const int b = g;
      if (tid < 32) {
        u64s4 hh, ll;
        hh.u = *(const unsigned long long*)&h2nh[b * H2 + 4 * tid];
        ll.u = *(const unsigned long long*)&h2nl[b * H2 + 4 * tid];
#pragma unroll
        for (int j = 0; j < 4; ++j)
          u.c.h2f[4 * tid + j] = bf2f((unsigned short)hh.s[j]) + bf2f((unsigned short)ll.s[j]);
      }
      __syncthreads();
      if (tid < P) {
        float a = p.bq[tid];
        const float* wr = &p.Wq[tid * H2];
#pragma unroll 8
        for (int k = 0; k < H2; k += 4) {
          float4 wv = *(const float4*)&wr[k];
          a += wv.x * u.c.h2f[k] + wv.y * u.c.h2f[k + 1] +
               wv.z * u.c.h2f[k + 2] + wv.w * u.c.h2f[k + 3];
        }
        u.c.qv[tid] = a;
      }
      __syncthreads();
      const float scale = 0.08838834764831845f;
      const int len = p.lens[b];
      if (tid < S) {
        const uint4* kr = (const uint4*)&p.keys[((size_t)b * S + tid) * P];
        float a = 0.0f;
#pragma unroll
        for (int k8 = 0; k8 < 16; ++k8) {
          uint4 uu = kr[k8];
          const float* q8 = &u.c.qv[k8 * 8];
          a += __uint_as_float(uu.x << 16) * q8[0] + __uint_as_float(uu.x & 0xffff0000u) * q8[1];
          a += __uint_as_float(uu.y << 16) * q8[2] + __uint_as_float(uu.y & 0xffff0000u) * q8[3];
          a += __uint_as_float(uu.z << 16) * q8[4] + __uint_as_float(uu.z & 0xffff0000u) * q8[5];
          a += __uint_as_float(uu.w << 16) * q8[6] + __uint_as_float(uu.w & 0xffff0000u) * q8[7];
        }
        a *= scale;
        if (tid >= len) a = -1e9f;
        u.c.sc[tid] = a;
      }
      __syncthreads();
      float m_ = (tid < S) ? u.c.sc[tid] : -INFINITY;
#pragma unroll
      for (int off = 32; off > 0; off >>= 1) m_ = fmaxf(m_, __shfl_xor(m_, off));
      if (lane == 0) u.c.red[w8] = m_;
      __syncthreads();
      float mx = u.c.red[0];
#pragma unroll
      for (int i = 1; i < 8; ++i) mx = fmaxf(mx, u.c.red[i]);
      __syncthreads();
      float e_ = 0.0f;
      if (tid < S) {
        e_ = expf(u.c.sc[tid] - mx);
        u.c.sc[tid] = e_;
      }
      float s_ = e_;
#pragma unroll
      for (int off = 32; off > 0; off >>= 1) s_ += __shfl_xor(s_, off);
      if (lane == 0) u.c.red[w8] = s_;
      __syncthreads();
      float ssum = u.c.red[0] + u.c.red[1] + u.c.red[2] + u.c.red[3] +
                   u.c.red[4] + u.c.red[5] + u.c.red[6] + u.c.red[7];
      const float inv = 1.0f / ssum;
      if (tid < S) {
        float wv = u.c.sc[tid] * inv;
        u.c.sc[tid] = wv;
        if (b == 0) p.out[PRED_SIZE + (size_t)t * S + tid] = wv;
      }
      __syncthreads();
      {
        const int qd = tid >> 7, pp = tid & 127;
        const uint2* vp = (const uint2*)(p.valuesT + ((size_t)b * P + pp) * S + qd * 100);
        const float* sp_ = &u.c.sc[qd * 100];
        float a = 0.0f;
#pragma unroll
        for (int i = 0; i < 25; ++i) {
          uint2 uu = vp[i];
          const float* s4 = &sp_[i * 4];
          a += __uint_as_float(uu.x << 16) * s4[0] + __uint_as_float(uu.x & 0xffff0000u) * s4[1];
          a += __uint_as_float(uu.y << 16) * s4[2] + __uint_as_float(uu.y & 0xffff0000u) * s4[3];
        }
        u.c.cpart[qd][pp] = a;
      }
      __syncthreads();
      if (tid < P) {
        float c = u.c.cpart[0][tid] + u.c.cpart[1][tid] + u.c.cpart[2][tid] + u.c.cpart[3][tid];
        u.c.ctxf[tid] = c;
      }
      __syncthreads();
      if (tid < 32) {
        unsigned short hb[4], lb[4];
#pragma unroll
        for (int j = 0; j < 4; ++j) {
          float c = u.c.ctxf[4 * tid + j];
          hb[j] = f2bf(c);
          lb[j] = f2bf(c - bf2f(hb[j]));
        }
        astore64(&ctnh[b * P + 4 * tid], pack4us(hb));
        astore64(&ctnl[b * P + 4 * tid], pack4us(lb));
      }
      __syncthreads();
      {
        const int g3 = tid >> 4, l4 = tid & 15;
        if (g3 < V) {
          float a = 0.0f;
          const float* er = &p.emb[g3 * EMB + l4 * 16];
#pragma unroll
          for (int i = 0; i < 4; ++i) {
            float4 e4 = *(const float4*)&er[i * 4];
            int k0 = l4 * 16 + i * 4;
            float x0 = (k0 + 0 < P) ? u.c.ctxf[k0 + 0] : u.c.h2f[k0 + 0 - P];
            float x1 = (k0 + 1 < P) ? u.c.ctxf[k0 + 1] : u.c.h2f[k0 + 1 - P];
            float x2 = (k0 + 2 < P) ? u.c.ctxf[k0 + 2] : u.c.h2f[k0 + 2 - P];
            float x3 = (k0 + 3 < P) ? u.c.ctxf[k0 + 3] : u.c.h2f[k0 + 3 - P];
            a += e4.x * x0 + e4.y * x1 + e4.z * x2 + e4.w * x3;
          }
          a += __shfl_xor(a, 8);
          a += __shfl_xor(a, 4);
          a += __shfl_xor(a, 2);
          a += __shfl_xor(a, 1);
          if (l4 == 0) p.out[((size_t)b * V + g3) * T + t] = a + p.b_out[g3];
        }
      }
    }
    gsync(p.flags, p.gen, ++expect, (t & 31) == 31);
  }
}

extern "C" void kernel_launch(void* const* d_in, const int* in_sizes, int n_in,
                              void* d_out, int out_size, void* d_ws, size_t ws_size,
                              hipStream_t stream) {
  const float* enc  = (const float*)d_in[0];
  const int*   lens = (const int*)d_in[1];
  const int*   y    = (const int*)d_in[2];
  const float* emb  = (const float*)d_in[3];
  const float* Wih1 = (const float*)d_in[4];
  const float* Whh1 = (const float*)d_in[5];
  const float* bih1 = (const float*)d_in[6];
  const float* bhh1 = (const float*)d_in[7];
  const float* Wih2 = (const float*)d_in[8];
  const float* Whh2 = (const float*)d_in[9];
  const float* bih2 = (const float*)d_in[10];
  const float* bhh2 = (const float*)d_in[11];
  const float* Wk   = (const float*)d_in[12];
  const float* bk   = (const float*)d_in[13];
  const float* Wv   = (const float*)d_in[14];
  const float* bv   = (const float*)d_in[15];
  const float* Wq   = (const float*)d_in[16];
  const float* bq   = (const float*)d_in[17];
  const float* b_out= (const float*)d_in[18];
  float* out = (float*)d_out;

  // ---- workspace layout ----
  char* cur = (char*)d_ws;
  unsigned* flags = (unsigned*)cur;             cur += 1024;
  unsigned* gen = flags + 128;
  float* c1 = (float*)cur;                      cur += (size_t)B * H1 * 4;  // [h][b]
  float* c2 = (float*)cur;                      cur += (size_t)B * H2 * 4;  // [h][b]
  const size_t zero_bytes = (size_t)cur - (size_t)d_ws;
  unsigned short* h1h = (unsigned short*)cur;   cur += (size_t)RING * B * H1 * 2;  // 8 MB
  unsigned short* h1l = (unsigned short*)cur;   cur += (size_t)RING * B * H1 * 2;
  unsigned short* h2h = (unsigned short*)cur;   cur += (size_t)RING * B * H2 * 2;  // 2 MB
  unsigned short* h2l = (unsigned short*)cur;   cur += (size_t)RING * B * H2 * 2;
  unsigned short* cth = (unsigned short*)cur;   cur += (size_t)RING * B * P * 2;   // 2 MB
  unsigned short* ctl = (unsigned short*)cur;   cur += (size_t)RING * B * P * 2;
  float* b1r = (float*)cur;                     cur += (size_t)N1 * 4;
  float* b2r = (float*)cur;                     cur += (size_t)N2 * 4;
  float* EmbW1 = (float*)cur;                   cur += (size_t)V * N1 * 4;
  unsigned short* keys    = (unsigned short*)cur; cur += (size_t)B * S * P * 2;
  unsigned short* valuesT = (unsigned short*)cur; cur += (size_t)B * S * P * 2;
  unsigned short* W1h = (unsigned short*)cur;   cur += (size_t)N1 * K1R * 2;
  unsigned short* W1l = (unsigned short*)cur;   cur += (size_t)N1 * K1R * 2;
  unsigned short* W2h = (unsigned short*)cur;   cur += (size_t)N2 * K2 * 2;
  unsigned short* W2l = (unsigned short*)cur;   cur += (size_t)N2 * K2 * 2;

  hipMemsetAsync(d_ws, 0, zero_bytes, stream);          // flags + c1 + c2
  hipMemsetAsync(h1h, 0, (size_t)B * H1 * 2, stream);   // ring slot 0 (t=0 prev state)
  hipMemsetAsync(h1l, 0, (size_t)B * H1 * 2, stream);
  hipMemsetAsync(h2h, 0, (size_t)B * H2 * 2, stream);
  hipMemsetAsync(h2l, 0, (size_t)B * H2 * 2, stream);

  prep_weights<<<2048, 256, 0, stream>>>(Wih1, Whh1, bih1, bhh1, Wih2, Whh2,
                                         bih2, bhh2, W1h, W1l, W2h, W2l, b1r, b2r);
  emb_w1<<<(V * N1 + 255) / 256, 256, 0, stream>>>(emb, Wih1, EmbW1);
  kv_gemm<<<dim3((B * S) / 64, 4), 256, 0, stream>>>(enc, Wk, bk, Wv, bv, keys, valuesT);
  ctx0_mean<<<B, P, 0, stream>>>(valuesT, cth, ctl);    // ctx ring slot 0

  DecParams prm;
  prm.W1h = W1h; prm.W1l = W1l; prm.W2h = W2h; prm.W2l = W2l;
  prm.b1r = b1r; prm.b2r = b2r; prm.EmbW1 = EmbW1;
  prm.y = y; prm.lens = lens;
  prm.Wq = Wq; prm.bq = bq; prm.emb = emb; prm.b_out = b_out;
  prm.keys = keys; prm.valuesT = valuesT;
  prm.h1h = h1h; prm.h1l = h1l; prm.h2h = h2h; prm.h2l = h2l;
  prm.cth = cth; prm.ctl = ctl;
  prm.c1 = c1; prm.c2 = c2;
  prm.out = out;
  prm.flags = flags; prm.gen = gen;

  void* kargs[] = { &prm };
  hipLaunchCooperativeKernel((const void*)decoder_loop, dim3(NBLK), dim3(NTHR),
                             kargs, 0, stream);
}